// Round 5
// baseline (1081.128 us; speedup 1.0000x reference)
//
#include <hip/hip_runtime.h>
#include <hip/hip_bf16.h>
#include <math.h>

// Problem constants
#define BB 4
#define C_IN 256
#define HH 256
#define WW 256
#define LL 5000
#define N_PTS0 32
#define N_PTS1 8
#define DIM_LOI 128
#define DIM_FC 1024
#define N_OUT_LINE 2500
#define MM (BB * LL)          // 20000
#define PIX (HH * WW)         // 65536
#define NGRP (MM * N_PTS1)    // 160000 pool groups

typedef __attribute__((ext_vector_type(8))) short short8_t;   // 8 bf16 in 4 VGPRs
typedef __attribute__((ext_vector_type(4))) float float4v;

// float -> bf16 (RNE) bit tricks
__device__ __forceinline__ short f2bf(float f) {
    union { float f; unsigned u; } c; c.f = f;
    unsigned u = c.u;
    u += 0x7FFFu + ((u >> 16) & 1u);
    return (short)(u >> 16);
}
__device__ __forceinline__ float bf2f(short h) {
    union { unsigned u; float f; } c; c.u = ((unsigned)(unsigned short)h) << 16;
    return c.f;
}

// async global->LDS DMA, 16 B per lane; dest = wave-uniform base + lane*16
__device__ __forceinline__ void load_lds16(const void* g, void* l) {
    __builtin_amdgcn_global_load_lds(
        (const __attribute__((address_space(1))) void*)g,
        (__attribute__((address_space(3))) void*)l, 16, 0, 0);
}

// raw barrier (NO vmcnt drain) with compiler-level memory fences so memory ops
// (ds_read / global_load_lds) cannot be moved across it
__device__ __forceinline__ void wave_barrier() {
    asm volatile("" ::: "memory");
    __builtin_amdgcn_s_barrier();
    asm volatile("" ::: "memory");
}

#define MFMA_B16(a, b, c) \
    c = __builtin_amdgcn_mfma_f32_16x16x32_bf16(a, b, c, 0, 0, 0)

// ---------------------------------------------------------------------------
// Kernel 1: 1x1 conv as bf16x3 MFMA GEMM (unchanged).
// ---------------------------------------------------------------------------
__global__ __launch_bounds__(256) void conv_mfma_kernel(
    const float* __restrict__ feat,   // [B, 256, PIX]
    const short* __restrict__ whi,    // [128, 256] bf16 hi
    const short* __restrict__ wlo,    // [128, 256] bf16 lo
    const float* __restrict__ bias,   // [128]
    float* __restrict__ x)            // [B*PIX, 128]
{
    __shared__ short As_hi[128][40];
    __shared__ short As_lo[128][40];
    __shared__ short Ws_hi[128][40];
    __shared__ short Ws_lo[128][40];

    const int t  = threadIdx.x;
    const int m0 = blockIdx.x * 128;
    const int b  = m0 >> 16;
    const int p0 = m0 & (PIX - 1);
    const float* fb = feat + (size_t)b * C_IN * PIX + p0;

    const int w = t >> 6, lane = t & 63;
    const int wmb = (w >> 1) * 64, wnb = (w & 1) * 64;
    const int fr = lane & 15;
    const int koff = (lane >> 4) << 3;

    const int sp = t & 127;
    const int cg = t >> 7;

    float4v acc[4][4];
#pragma unroll
    for (int mi = 0; mi < 4; mi++)
#pragma unroll
        for (int ni = 0; ni < 4; ni++)
            acc[mi][ni] = (float4v){0.f, 0.f, 0.f, 0.f};

    for (int k0 = 0; k0 < C_IN; k0 += 32) {
#pragma unroll
        for (int i = 0; i < 2; i++) {
            int idx = t + (i << 8);
            int row = idx >> 2;
            int kc  = (idx & 3) << 3;
            *(int4*)&Ws_hi[row][kc] = *(const int4*)(whi + row * C_IN + k0 + kc);
            *(int4*)&Ws_lo[row][kc] = *(const int4*)(wlo + row * C_IN + k0 + kc);
        }
#pragma unroll
        for (int j = 0; j < 8; j++) {
            int c = cg * 16 + j * 2;
            float v0 = fb[(size_t)(k0 + c) * PIX + sp];
            float v1 = fb[(size_t)(k0 + c + 1) * PIX + sp];
            short h0 = f2bf(v0), h1 = f2bf(v1);
            short l0 = f2bf(v0 - bf2f(h0)), l1 = f2bf(v1 - bf2f(h1));
            *(unsigned*)&As_hi[sp][c] =
                (unsigned)(unsigned short)h0 | ((unsigned)(unsigned short)h1 << 16);
            *(unsigned*)&As_lo[sp][c] =
                (unsigned)(unsigned short)l0 | ((unsigned)(unsigned short)l1 << 16);
        }
        __syncthreads();

        short8_t ah[4], al[4];
#pragma unroll
        for (int mi = 0; mi < 4; mi++) {
            ah[mi] = *(const short8_t*)&As_hi[wmb + mi * 16 + fr][koff];
            al[mi] = *(const short8_t*)&As_lo[wmb + mi * 16 + fr][koff];
        }
#pragma unroll
        for (int ni = 0; ni < 4; ni++) {
            short8_t bh = *(const short8_t*)&Ws_hi[wnb + ni * 16 + fr][koff];
            short8_t bl = *(const short8_t*)&Ws_lo[wnb + ni * 16 + fr][koff];
#pragma unroll
            for (int mi = 0; mi < 4; mi++) {
                MFMA_B16(ah[mi], bh, acc[mi][ni]);
                MFMA_B16(al[mi], bh, acc[mi][ni]);
                MFMA_B16(ah[mi], bl, acc[mi][ni]);
            }
        }
        __syncthreads();
    }

#pragma unroll
    for (int ni = 0; ni < 4; ni++) {
        int ncol = wnb + ni * 16 + fr;
        float bv = bias[ncol];
#pragma unroll
        for (int mi = 0; mi < 4; mi++) {
            int r0 = m0 + wmb + mi * 16 + ((lane >> 4) << 2);
#pragma unroll
            for (int i2 = 0; i2 < 4; i2++) {
                x[(size_t)(r0 + i2) * 128 + ncol] = acc[mi][ni][i2] + bv;
            }
        }
    }
}

// ---------------------------------------------------------------------------
// Group sort: counting sort of 160K pool-groups by (batch, 32x32-px cell of
// first point). Processing sorted groups gives concurrent waves spatial
// locality in x -> L3 reuse instead of HBM re-fetch.
// ---------------------------------------------------------------------------
__global__ __launch_bounds__(256) void zero_hist_kernel(int* __restrict__ hist)
{
    hist[threadIdx.x] = 0;
}

__global__ __launch_bounds__(256) void group_key_kernel(
    const float* __restrict__ lines, int* __restrict__ key, int* __restrict__ hist)
{
    const int gid = blockIdx.x * 256 + threadIdx.x;
    if (gid >= NGRP) return;
    const int bl = gid >> 3, g = gid & 7;
    const float* lp = lines + (size_t)bl * 4;
    const float lam = (float)((double)(g * 4) / 31.0);
    float px = lp[0] * lam + lp[2] * (1.0f - lam) - 0.5f;
    float py = lp[1] * lam + lp[3] * (1.0f - lam) - 0.5f;
    int ix = min(max((int)floorf(px), 0), 255);
    int iy = min(max((int)floorf(py), 0), 255);
    const int b = bl / LL;
    const int k = b * 64 + (ix >> 5) * 8 + (iy >> 5);
    key[gid] = k;
    atomicAdd(&hist[k], 1);
}

__global__ __launch_bounds__(256) void scan_kernel(
    const int* __restrict__ hist, int* __restrict__ cursor)
{
    __shared__ int sh[256];
    const int t = threadIdx.x;
    const int h = hist[t];
    sh[t] = h;
    __syncthreads();
#pragma unroll
    for (int off = 1; off < 256; off <<= 1) {
        int u = (t >= off) ? sh[t - off] : 0;
        __syncthreads();
        sh[t] += u;
        __syncthreads();
    }
    cursor[t] = sh[t] - h;    // exclusive prefix
}

__global__ __launch_bounds__(256) void scatter_kernel(
    const int* __restrict__ key, int* __restrict__ cursor, int* __restrict__ perm)
{
    const int gid = blockIdx.x * 256 + threadIdx.x;
    if (gid >= NGRP) return;
    const int k = key[gid];
    const int pos = atomicAdd(&cursor[k], 1);
    perm[pos] = gid;
}

// ---------------------------------------------------------------------------
// Kernel 2 v3: bilinear sample + maxpool over SORTED pool-groups.
//  One group (4 points) per 32-thread slice; 8 groups per 256-thread block,
//  taken consecutively from perm so resident blocks share an image region.
//  Output layout is GROUP-MAJOR: pooled[bl][g*128+ch] (fully coalesced
//  512 B/group writes); w1 is split with the matching k-permutation so the
//  fc GEMM is unchanged mathematically.
//  Interpolation arithmetic identical to v2 (same fp32 expression order).
// ---------------------------------------------------------------------------
__global__ __launch_bounds__(256) void sample_pool_kernel(
    const float* __restrict__ lines,
    const float* __restrict__ x,
    const int* __restrict__ perm,
    short* __restrict__ phi,
    short* __restrict__ plo)
{
    const int t  = threadIdx.x;
    const int pg = perm[blockIdx.x * 8 + (t >> 5)];
    const int bl = pg >> 3, g = pg & 7;
    const int b  = bl / LL;
    const int cg = t & 31;                      // channel group (4 ch)
    const float* lp = lines + (size_t)bl * 4;
    const float p0r = lp[0], p0c = lp[1], p1r = lp[2], p1c = lp[3];
    const float* xb = x + (size_t)b * PIX * 128 + cg * 4;

    float mx0 = -INFINITY, mx1 = -INFINITY, mx2 = -INFINITY, mx3 = -INFINITY;
#pragma unroll
    for (int j = 0; j < 4; j++) {
        int tt = g * 4 + j;
        float lam = (float)((double)tt / 31.0);
        float px = p0r * lam + p1r * (1.0f - lam) - 0.5f;
        float py = p0c * lam + p1c * (1.0f - lam) - 0.5f;
        float px0 = fminf(fmaxf(floorf(px), 0.0f), 255.0f);
        float py0 = fminf(fmaxf(floorf(py), 0.0f), 255.0f);
        float px1 = fminf(px0 + 1.0f, 255.0f);
        float py1 = fminf(py0 + 1.0f, 255.0f);
        int ix0 = (int)px0, iy0 = (int)py0, ix1 = (int)px1, iy1 = (int)py1;
        float wx1 = px1 - px, wx0 = px - px0;
        float wy1 = py1 - py, wy0 = py - py0;
        float w00 = wx1 * wy1, w10 = wx0 * wy1;
        float w01 = wx1 * wy0, w11 = wx0 * wy0;
        float4 v00 = *(const float4*)(xb + (size_t)(ix0 * WW + iy0) * 128);
        float4 v10 = *(const float4*)(xb + (size_t)(ix1 * WW + iy0) * 128);
        float4 v01 = *(const float4*)(xb + (size_t)(ix0 * WW + iy1) * 128);
        float4 v11 = *(const float4*)(xb + (size_t)(ix1 * WW + iy1) * 128);
        mx0 = fmaxf(mx0, v00.x * w00 + v10.x * w10 + v01.x * w01 + v11.x * w11);
        mx1 = fmaxf(mx1, v00.y * w00 + v10.y * w10 + v01.y * w01 + v11.y * w11);
        mx2 = fmaxf(mx2, v00.z * w00 + v10.z * w10 + v01.z * w01 + v11.z * w11);
        mx3 = fmaxf(mx3, v00.w * w00 + v10.w * w10 + v01.w * w01 + v11.w * w11);
    }
    float mxs[4] = {mx0, mx1, mx2, mx3};
    short4 h4, l4;
    short hs[4], ls[4];
#pragma unroll
    for (int k = 0; k < 4; k++) {
        hs[k] = f2bf(mxs[k]);
        ls[k] = f2bf(mxs[k] - bf2f(hs[k]));
    }
    h4.x = hs[0]; h4.y = hs[1]; h4.z = hs[2]; h4.w = hs[3];
    l4.x = ls[0]; l4.y = ls[1]; l4.z = ls[2]; l4.w = ls[3];
    const size_t o = (size_t)bl * 1024 + g * 128 + cg * 4;   // group-major
    *(short4*)(phi + o) = h4;
    *(short4*)(plo + o) = l4;
}

// ---------------------------------------------------------------------------
// Kernel 2b: split fp32 weights into bf16 hi/lo (unchanged; fc1 & w2).
// ---------------------------------------------------------------------------
__global__ __launch_bounds__(256) void split_kernel(
    const float* __restrict__ w, short* __restrict__ hi, short* __restrict__ lo)
{
    const int i = (blockIdx.x * 256 + threadIdx.x) * 4;
    float4 v = *(const float4*)(w + i);
    float vv[4] = {v.x, v.y, v.z, v.w};
    short4 h, l;
    short hs[4], ls[4];
#pragma unroll
    for (int j = 0; j < 4; j++) {
        hs[j] = f2bf(vv[j]);
        ls[j] = f2bf(vv[j] - bf2f(hs[j]));
    }
    h.x = hs[0]; h.y = hs[1]; h.z = hs[2]; h.w = hs[3];
    l.x = ls[0]; l.y = ls[1]; l.z = ls[2]; l.w = ls[3];
    *(short4*)(hi + i) = h;
    *(short4*)(lo + i) = l;
}

// ---------------------------------------------------------------------------
// Kernel 2c: split w1 with k-permutation k' = g*128+ch (src k = ch*8+g),
// matching the group-major pooled layout.
// ---------------------------------------------------------------------------
__global__ __launch_bounds__(256) void split_permute_kernel(
    const float* __restrict__ w, short* __restrict__ hi, short* __restrict__ lo)
{
    const int i = (blockIdx.x * 256 + threadIdx.x) * 4;   // d*1024 + kp
    const int d = i >> 10, kp = i & 1023;
    const int g = kp >> 7, ch = kp & 127;                 // 4-chunk never crosses g
    float vv[4];
#pragma unroll
    for (int j = 0; j < 4; j++)
        vv[j] = w[(size_t)d * 1024 + (ch + j) * 8 + g];
    short4 h, l;
    short hs[4], ls[4];
#pragma unroll
    for (int j = 0; j < 4; j++) {
        hs[j] = f2bf(vv[j]);
        ls[j] = f2bf(vv[j] - bf2f(hs[j]));
    }
    h.x = hs[0]; h.y = hs[1]; h.z = hs[2]; h.w = hs[3];
    l.x = ls[0]; l.y = ls[1]; l.z = ls[2]; l.w = ls[3];
    *(short4*)(hi + i) = h;
    *(short4*)(lo + i) = l;
}

// ---------------------------------------------------------------------------
// Kernel 3 v4: bf16x3 MFMA GEMM-NT, compiler-pipelined tile body (unchanged).
// ---------------------------------------------------------------------------
#define NT 32                 // K tiles (1024 / 32)
#define BUFS 28672            // shorts per buffer (56 KB)
#define A_LO 6144             // [192][32] hi at 0, lo at 6144
#define B_HI 12288            // [256][32] hi
#define B_LO 20480            // [256][32] lo

template <bool SPLIT_OUT>
__global__ __launch_bounds__(512, 2) void gemm_bf16x3_v4(
    const short* __restrict__ Ahi, const short* __restrict__ Alo,
    const short* __restrict__ Bhi, const short* __restrict__ Blo,
    const float* __restrict__ bias,
    float* __restrict__ Cf, short* __restrict__ Chi, short* __restrict__ Clo,
    int M, int Mtiles)
{
    __shared__ short lds[2 * BUFS];   // 112 KB

    const int t   = threadIdx.x;
    const int bid = blockIdx.x;
    // bijective XCD chunking (m204): nwg = Mtiles*4, xcd = bid&7
    const int nwg = Mtiles * 4;
    const int q = nwg >> 3, r = nwg & 7;
    const int xcd = bid & 7, seq = bid >> 3;
    const int wgid = ((xcd < r) ? xcd * (q + 1) : r * (q + 1) + (xcd - r) * q) + seq;
    const int tileM = wgid >> 2, tileN = wgid & 3;   // M-major: same-A adjacent
    const int m0 = tileM * 192, n0 = tileN * 256;

    const int w = t >> 6, lane = t & 63;
    const int wr = w >> 2;            // 0..1 -> M offset wr*96
    const int wc = w & 3;             // 0..3 -> N offset wc*64
    const int fr = lane & 15;
    // swizzled read chunk: (lane>>4) ^ ((row>>1)&3), row ≡ fr (mod 16)
    const int ksw = (((lane >> 4) ^ ((lane >> 1) & 3)) << 3);
    const int a_row = wr * 96 + fr;
    const int b_row = wc * 64 + fr;

    // --- DMA descriptors: 7 chunks/wave, 56 chunks = 56 KB per K-tile
    const short* gp[7];
    int lp[7];
    {
        const int csrc = (lane & 3) ^ ((lane >> 3) & 3);  // source chunk permute
#pragma unroll
        for (int s = 0; s < 7; s++) {
            int e = w * 7 + s;                            // 0..55
            const short* mp; int mo, j, grow;
            int rl = lane >> 2;                           // row within 16-row chunk
            if (e < 12)      { mp = Ahi; mo = 0;    j = e;      grow = min(m0 + j * 16 + rl, M - 1); }
            else if (e < 24) { mp = Alo; mo = A_LO; j = e - 12; grow = min(m0 + j * 16 + rl, M - 1); }
            else if (e < 40) { mp = Bhi; mo = B_HI; j = e - 24; grow = n0 + j * 16 + rl; }
            else             { mp = Blo; mo = B_LO; j = e - 40; grow = n0 + j * 16 + rl; }
            gp[s] = mp + (size_t)grow * 1024 + csrc * 8;
            lp[s] = mo + j * 512 + lane * 8;              // linear dest, lane*16B
        }
    }

    // --- prologue: tile0 -> buf0, tile1 -> buf1; wait tile0 only (vmcnt(7))
#pragma unroll
    for (int s = 0; s < 7; s++) { load_lds16(gp[s], &lds[lp[s]]); gp[s] += 32; }
#pragma unroll
    for (int s = 0; s < 7; s++) { load_lds16(gp[s], &lds[BUFS + lp[s]]); gp[s] += 32; }
    asm volatile("s_waitcnt vmcnt(7)" ::: "memory");
    wave_barrier();

    float4v acc[6][4];
#pragma unroll
    for (int mf = 0; mf < 6; mf++)
#pragma unroll
        for (int nf = 0; nf < 4; nf++)
            acc[mf][nf] = (float4v){0.f, 0.f, 0.f, 0.f};

    for (int kt = 0; kt < NT; ++kt) {
        const int off = (kt & 1) * BUFS;

        // B fragments for the whole tile (8 reads), then per-M-frag A reads;
        // no lgkmcnt(0) pin: compiler interleaves MFMA with in-flight reads.
        short8_t bh[4], bl[4];
#pragma unroll
        for (int nf = 0; nf < 4; nf++) {
            bh[nf] = *(const short8_t*)&lds[off + B_HI + (b_row + nf * 16) * 32 + ksw];
            bl[nf] = *(const short8_t*)&lds[off + B_LO + (b_row + nf * 16) * 32 + ksw];
        }
#pragma unroll
        for (int mf = 0; mf < 6; mf++) {
            short8_t ah = *(const short8_t*)&lds[off + (a_row + mf * 16) * 32 + ksw];
            short8_t al = *(const short8_t*)&lds[off + A_LO + (a_row + mf * 16) * 32 + ksw];
#pragma unroll
            for (int nf = 0; nf < 4; nf++) {
                MFMA_B16(ah, bh[nf], acc[mf][nf]);
                MFMA_B16(al, bh[nf], acc[mf][nf]);
                MFMA_B16(ah, bl[nf], acc[mf][nf]);
            }
        }

        if (kt < NT - 1) {
            wave_barrier();               // all reads of buf[cur] consumed
            if (kt + 2 < NT) {
                // stage tile kt+2 into buf[cur]; lands during tile kt+1
#pragma unroll
                for (int s = 0; s < 7; s++) {
                    load_lds16(gp[s], &lds[off + lp[s]]); gp[s] += 32;
                }
                asm volatile("s_waitcnt vmcnt(7)" ::: "memory");  // kt+1 landed
            } else {
                asm volatile("s_waitcnt vmcnt(0)" ::: "memory");  // drain last
            }
            wave_barrier();               // publish buf for tile kt+1
        }
    }

    // ---- epilogue
#pragma unroll
    for (int nf = 0; nf < 4; nf++) {
        int ncol = n0 + wc * 64 + nf * 16 + fr;
        float bv = bias[ncol];
#pragma unroll
        for (int mf = 0; mf < 6; mf++) {
            int r0 = m0 + wr * 96 + mf * 16 + ((lane >> 4) << 2);
#pragma unroll
            for (int i2 = 0; i2 < 4; i2++) {
                int rr = r0 + i2;
                if (rr < M) {
                    float v = fmaxf(acc[mf][nf][i2] + bv, 0.0f);
                    if (SPLIT_OUT) {
                        short h = f2bf(v);
                        Chi[(size_t)rr * 1024 + ncol] = h;
                        Clo[(size_t)rr * 1024 + ncol] = f2bf(v - bf2f(h));
                    } else {
                        Cf[(size_t)rr * 1024 + ncol] = v;
                    }
                }
            }
        }
    }
}

// ---------------------------------------------------------------------------
// Kernel 4: fc3 (N=4) + softmax + mask + argmax-class key (unchanged).
// ---------------------------------------------------------------------------
__global__ __launch_bounds__(256) void fc3_softmax_kernel(
    const float* __restrict__ h2, const float* __restrict__ w3,
    const float* __restrict__ b3, float* __restrict__ s, int* __restrict__ keys)
{
    const int m = blockIdx.x * 4 + (threadIdx.x >> 6);
    const int lane = threadIdx.x & 63;
    const float* hp = h2 + (size_t)m * DIM_FC;
    float a0 = 0.f, a1 = 0.f, a2 = 0.f, a3 = 0.f;
    for (int k = lane; k < DIM_FC; k += 64) {
        float hv = hp[k];
        a0 = fmaf(hv, w3[k], a0);
        a1 = fmaf(hv, w3[DIM_FC + k], a1);
        a2 = fmaf(hv, w3[2 * DIM_FC + k], a2);
        a3 = fmaf(hv, w3[3 * DIM_FC + k], a3);
    }
#pragma unroll
    for (int off = 32; off > 0; off >>= 1) {
        a0 += __shfl_down(a0, off, 64);
        a1 += __shfl_down(a1, off, 64);
        a2 += __shfl_down(a2, off, 64);
        a3 += __shfl_down(a3, off, 64);
    }
    if (lane == 0) {
        float l0 = a0 + b3[0], l1 = a1 + b3[1], l2 = a2 + b3[2], l3 = a3 + b3[3];
        float mxl = fmaxf(fmaxf(l0, l1), fmaxf(l2, l3));
        float e0 = expf(l0 - mxl), e1 = expf(l1 - mxl);
        float e2 = expf(l2 - mxl), e3 = expf(l3 - mxl);
        float inv = 1.0f / (e0 + e1 + e2 + e3);
        float s0 = e0 * inv, s1 = e1 * inv, s2 = e2 * inv, s3 = e3 * inv;
        float* sp = s + (size_t)m * 4;
        sp[0] = s0; sp[1] = s1; sp[2] = s2; sp[3] = s3;
        int best = 0; float bv = s0;
        if (s1 > bv) { best = 1; bv = s1; }
        if (s2 > bv) { best = 2; bv = s2; }
        if (s3 > bv) { best = 3; bv = s3; }
        bool msk = ((s1 > 0.25f) || (s2 > 0.25f) || (s3 > 0.25f)) && (s0 < 0.25f);
        keys[m] = msk ? best : -1;
    }
}

// ---------------------------------------------------------------------------
// Kernel 5: stable counting sort by class descending (unchanged).
// ---------------------------------------------------------------------------
__global__ __launch_bounds__(64) void order_kernel(
    const int* __restrict__ keys, int* __restrict__ ord, int* __restrict__ cnts)
{
    const int b = blockIdx.x;
    const int lane = threadIdx.x;
    const int* kb = keys + b * LL;
    int c0 = 0, c1 = 0, c2 = 0, c3 = 0;
    for (int line = lane; line < LL; line += 64) {
        int k = kb[line];
        c0 += (k == 0); c1 += (k == 1); c2 += (k == 2); c3 += (k == 3);
    }
#pragma unroll
    for (int off = 32; off > 0; off >>= 1) {
        c0 += __shfl_down(c0, off, 64);
        c1 += __shfl_down(c1, off, 64);
        c2 += __shfl_down(c2, off, 64);
        c3 += __shfl_down(c3, off, 64);
    }
    int t0 = __shfl(c0, 0, 64), t1 = __shfl(c1, 0, 64);
    int t2 = __shfl(c2, 0, 64), t3 = __shfl(c3, 0, 64);
    if (lane == 0) cnts[b] = t0 + t1 + t2 + t3;
    int base[4];
    base[3] = 0; base[2] = t3; base[1] = t3 + t2; base[0] = t3 + t2 + t1;
    int run[4] = {0, 0, 0, 0};
    const unsigned long long below = (1ull << lane) - 1ull;
    int* ob = ord + b * LL;
    for (int s0 = 0; s0 < LL; s0 += 64) {
        int line = s0 + lane;
        int k = (line < LL) ? kb[line] : -2;
#pragma unroll
        for (int kk = 0; kk < 4; kk++) {
            unsigned long long mask = __ballot(k == kk);
            if (k == kk) {
                int pos = base[kk] + run[kk] + __popcll(mask & below);
                ob[pos] = line;
            }
            run[kk] += __popcll(mask);
        }
    }
}

// ---------------------------------------------------------------------------
// Kernel 6: cyclic fill of 2500 outputs per batch (unchanged).
// ---------------------------------------------------------------------------
__global__ __launch_bounds__(256) void fill_kernel(
    const float* __restrict__ lines, const float* __restrict__ s,
    const int* __restrict__ ord, const int* __restrict__ cnts,
    float* __restrict__ out)
{
    const int i = blockIdx.x * 256 + threadIdx.x;
    if (i >= BB * N_OUT_LINE) return;
    const int b = i / N_OUT_LINE;
    const int j = i % N_OUT_LINE;
    const int cnt = cnts[b];
    float4 lo = {0.f, 0.f, 0.f, 0.f}, sc = {0.f, 0.f, 0.f, 0.f};
    if (cnt > 0) {
        int line = ord[b * LL + (j % cnt)];
        lo = *(const float4*)(lines + ((size_t)b * LL + line) * 4);
        sc = *(const float4*)(s + ((size_t)b * LL + line) * 4);
    }
    *(float4*)(out + (size_t)i * 4) = lo;
    *(float4*)(out + (size_t)(BB * N_OUT_LINE) * 4 + (size_t)i * 4) = sc;
}

// ---------------------------------------------------------------------------
extern "C" void kernel_launch(void* const* d_in, const int* in_sizes, int n_in,
                              void* d_out, int out_size, void* d_ws, size_t ws_size,
                              hipStream_t stream) {
    (void)in_sizes; (void)n_in; (void)out_size; (void)ws_size;
    const float* feature = (const float*)d_in[0];
    const float* lines   = (const float*)d_in[1];
    const float* fc1_w   = (const float*)d_in[2];
    const float* fc1_b   = (const float*)d_in[3];
    const float* w1      = (const float*)d_in[4];
    const float* b1      = (const float*)d_in[5];
    const float* w2      = (const float*)d_in[6];
    const float* b2      = (const float*)d_in[7];
    const float* w3      = (const float*)d_in[8];
    const float* b3      = (const float*)d_in[9];
    float* out = (float*)d_out;

    float* x = (float*)d_ws;
    short* pooled_hi = (short*)(x + (size_t)BB * PIX * 128);
    short* pooled_lo = pooled_hi + (size_t)MM * DIM_FC;
    short* h1hi = (short*)x;
    short* h1lo = h1hi + (size_t)MM * DIM_FC;
    float* h2 = (float*)pooled_hi;
    short* w1hi = (short*)((char*)d_ws + 100u * 1024u * 1024u);
    short* w1lo = w1hi + DIM_FC * DIM_FC;
    short* w2hi = w1lo + DIM_FC * DIM_FC;
    short* w2lo = w2hi + DIM_FC * DIM_FC;
    float* s    = (float*)(pooled_lo + (size_t)MM * DIM_FC);
    int* keys   = (int*)(s + MM * 4);
    int* ord    = keys + MM;
    int* cnts   = ord + MM;
    short* fc1hi = (short*)(cnts + 64);
    short* fc1lo = fc1hi + DIM_LOI * C_IN;
    // sort scratch directly after fc1lo (~217 MiB into 1 GiB ws)
    int* skey  = (int*)(fc1lo + DIM_LOI * C_IN);        // NGRP ints
    int* sperm = skey + NGRP;                           // NGRP ints
    int* shist = sperm + NGRP;                          // 256 ints
    int* scur  = shist + 256;                           // 256 ints

    split_kernel<<<(DIM_LOI * C_IN) / 1024, 256, 0, stream>>>(fc1_w, fc1hi, fc1lo);
    zero_hist_kernel<<<1, 256, 0, stream>>>(shist);
    group_key_kernel<<<(NGRP + 255) / 256, 256, 0, stream>>>(lines, skey, shist);
    scan_kernel<<<1, 256, 0, stream>>>(shist, scur);
    scatter_kernel<<<(NGRP + 255) / 256, 256, 0, stream>>>(skey, scur, sperm);
    conv_mfma_kernel<<<(BB * PIX) / 128, 256, 0, stream>>>(
        feature, fc1hi, fc1lo, fc1_b, x);
    sample_pool_kernel<<<NGRP / 8, 256, 0, stream>>>(
        lines, x, sperm, pooled_hi, pooled_lo);
    split_permute_kernel<<<DIM_FC * DIM_FC / 1024, 256, 0, stream>>>(w1, w1hi, w1lo);
    split_kernel<<<DIM_FC * DIM_FC / 1024, 256, 0, stream>>>(w2, w2hi, w2lo);

    // grid: Mtiles(105) x 4 N-tiles, 512 threads
    const int Mtiles = (MM + 191) / 192;   // 105
    gemm_bf16x3_v4<true><<<Mtiles * 4, 512, 0, stream>>>(
        pooled_hi, pooled_lo, w1hi, w1lo, b1, nullptr, h1hi, h1lo, MM, Mtiles);
    gemm_bf16x3_v4<false><<<Mtiles * 4, 512, 0, stream>>>(
        h1hi, h1lo, w2hi, w2lo, b2, h2, nullptr, nullptr, MM, Mtiles);

    fc3_softmax_kernel<<<MM / 4, 256, 0, stream>>>(h2, w3, b3, s, keys);
    order_kernel<<<BB, 64, 0, stream>>>(keys, ord, cnts);
    fill_kernel<<<(BB * N_OUT_LINE + 255) / 256, 256, 0, stream>>>(
        lines, s, ord, cnts, out);
}

// Round 6
// 882.423 us; speedup vs baseline: 1.2252x; 1.2252x over previous
//
#include <hip/hip_runtime.h>
#include <hip/hip_bf16.h>
#include <math.h>

// Problem constants
#define BB 4
#define C_IN 256
#define HH 256
#define WW 256
#define LL 5000
#define N_PTS0 32
#define N_PTS1 8
#define DIM_LOI 128
#define DIM_FC 1024
#define N_OUT_LINE 2500
#define MM (BB * LL)          // 20000
#define PIX (HH * WW)         // 65536
#define NGRP (MM * N_PTS1)    // 160000 pool groups
#define NSBLK (NGRP / 256)    // 625 sort blocks (exact)

typedef __attribute__((ext_vector_type(8))) short short8_t;   // 8 bf16 in 4 VGPRs
typedef __attribute__((ext_vector_type(4))) float float4v;

// float -> bf16 (RNE) bit tricks
__device__ __forceinline__ short f2bf(float f) {
    union { float f; unsigned u; } c; c.f = f;
    unsigned u = c.u;
    u += 0x7FFFu + ((u >> 16) & 1u);
    return (short)(u >> 16);
}
__device__ __forceinline__ float bf2f(short h) {
    union { unsigned u; float f; } c; c.u = ((unsigned)(unsigned short)h) << 16;
    return c.f;
}

// async global->LDS DMA, 16 B per lane; dest = wave-uniform base + lane*16
__device__ __forceinline__ void load_lds16(const void* g, void* l) {
    __builtin_amdgcn_global_load_lds(
        (const __attribute__((address_space(1))) void*)g,
        (__attribute__((address_space(3))) void*)l, 16, 0, 0);
}

// raw barrier (NO vmcnt drain) with compiler-level memory fences so memory ops
// (ds_read / global_load_lds) cannot be moved across it
__device__ __forceinline__ void wave_barrier() {
    asm volatile("" ::: "memory");
    __builtin_amdgcn_s_barrier();
    asm volatile("" ::: "memory");
}

#define MFMA_B16(a, b, c) \
    c = __builtin_amdgcn_mfma_f32_16x16x32_bf16(a, b, c, 0, 0, 0)

// ---------------------------------------------------------------------------
// Kernel 1: 1x1 conv as bf16x3 MFMA GEMM (unchanged).
// ---------------------------------------------------------------------------
__global__ __launch_bounds__(256) void conv_mfma_kernel(
    const float* __restrict__ feat,   // [B, 256, PIX]
    const short* __restrict__ whi,    // [128, 256] bf16 hi
    const short* __restrict__ wlo,    // [128, 256] bf16 lo
    const float* __restrict__ bias,   // [128]
    float* __restrict__ x)            // [B*PIX, 128]
{
    __shared__ short As_hi[128][40];
    __shared__ short As_lo[128][40];
    __shared__ short Ws_hi[128][40];
    __shared__ short Ws_lo[128][40];

    const int t  = threadIdx.x;
    const int m0 = blockIdx.x * 128;
    const int b  = m0 >> 16;
    const int p0 = m0 & (PIX - 1);
    const float* fb = feat + (size_t)b * C_IN * PIX + p0;

    const int w = t >> 6, lane = t & 63;
    const int wmb = (w >> 1) * 64, wnb = (w & 1) * 64;
    const int fr = lane & 15;
    const int koff = (lane >> 4) << 3;

    const int sp = t & 127;
    const int cg = t >> 7;

    float4v acc[4][4];
#pragma unroll
    for (int mi = 0; mi < 4; mi++)
#pragma unroll
        for (int ni = 0; ni < 4; ni++)
            acc[mi][ni] = (float4v){0.f, 0.f, 0.f, 0.f};

    for (int k0 = 0; k0 < C_IN; k0 += 32) {
#pragma unroll
        for (int i = 0; i < 2; i++) {
            int idx = t + (i << 8);
            int row = idx >> 2;
            int kc  = (idx & 3) << 3;
            *(int4*)&Ws_hi[row][kc] = *(const int4*)(whi + row * C_IN + k0 + kc);
            *(int4*)&Ws_lo[row][kc] = *(const int4*)(wlo + row * C_IN + k0 + kc);
        }
#pragma unroll
        for (int j = 0; j < 8; j++) {
            int c = cg * 16 + j * 2;
            float v0 = fb[(size_t)(k0 + c) * PIX + sp];
            float v1 = fb[(size_t)(k0 + c + 1) * PIX + sp];
            short h0 = f2bf(v0), h1 = f2bf(v1);
            short l0 = f2bf(v0 - bf2f(h0)), l1 = f2bf(v1 - bf2f(h1));
            *(unsigned*)&As_hi[sp][c] =
                (unsigned)(unsigned short)h0 | ((unsigned)(unsigned short)h1 << 16);
            *(unsigned*)&As_lo[sp][c] =
                (unsigned)(unsigned short)l0 | ((unsigned)(unsigned short)l1 << 16);
        }
        __syncthreads();

        short8_t ah[4], al[4];
#pragma unroll
        for (int mi = 0; mi < 4; mi++) {
            ah[mi] = *(const short8_t*)&As_hi[wmb + mi * 16 + fr][koff];
            al[mi] = *(const short8_t*)&As_lo[wmb + mi * 16 + fr][koff];
        }
#pragma unroll
        for (int ni = 0; ni < 4; ni++) {
            short8_t bh = *(const short8_t*)&Ws_hi[wnb + ni * 16 + fr][koff];
            short8_t bl = *(const short8_t*)&Ws_lo[wnb + ni * 16 + fr][koff];
#pragma unroll
            for (int mi = 0; mi < 4; mi++) {
                MFMA_B16(ah[mi], bh, acc[mi][ni]);
                MFMA_B16(al[mi], bh, acc[mi][ni]);
                MFMA_B16(ah[mi], bl, acc[mi][ni]);
            }
        }
        __syncthreads();
    }

#pragma unroll
    for (int ni = 0; ni < 4; ni++) {
        int ncol = wnb + ni * 16 + fr;
        float bv = bias[ncol];
#pragma unroll
        for (int mi = 0; mi < 4; mi++) {
            int r0 = m0 + wmb + mi * 16 + ((lane >> 4) << 2);
#pragma unroll
            for (int i2 = 0; i2 < 4; i2++) {
                x[(size_t)(r0 + i2) * 128 + ncol] = acc[mi][ni][i2] + bv;
            }
        }
    }
}

// ---------------------------------------------------------------------------
// Group sort v2: stable counting sort of 160K pool-groups by
// (batch, 32x32-px cell), with NO global atomics (round-5's two
// 160K-global-atomic kernels on 16 cache lines cost ~200 us).
//  A: per-block LDS histogram -> blockHist[625][256] (coalesced writes)
//  B: one block: per-bin totals (coalesced), exclusive scan over bins,
//     per-(block,bin) running bases
//  C: LDS cursors from bases + LDS atomicAdd -> perm (exact permutation,
//     stable; perm order has no numeric effect)
// ---------------------------------------------------------------------------
__global__ __launch_bounds__(256) void hist_key_kernel(
    const float* __restrict__ lines, int* __restrict__ key,
    int* __restrict__ blockHist)
{
    __shared__ int h[256];
    const int t = threadIdx.x;
    h[t] = 0;
    __syncthreads();
    const int gid = blockIdx.x * 256 + t;
    const int bl = gid >> 3, g = gid & 7;
    const float* lp = lines + (size_t)bl * 4;
    const float lam = (float)((double)(g * 4) / 31.0);
    float px = lp[0] * lam + lp[2] * (1.0f - lam) - 0.5f;
    float py = lp[1] * lam + lp[3] * (1.0f - lam) - 0.5f;
    int ix = min(max((int)floorf(px), 0), 255);
    int iy = min(max((int)floorf(py), 0), 255);
    const int b = bl / LL;
    const int k = b * 64 + (ix >> 5) * 8 + (iy >> 5);
    key[gid] = k;
    atomicAdd(&h[k], 1);          // LDS atomic
    __syncthreads();
    blockHist[blockIdx.x * 256 + t] = h[t];
}

__global__ __launch_bounds__(256) void offset_kernel(
    const int* __restrict__ blockHist, int* __restrict__ base)
{
    __shared__ int sh[256];
    const int t = threadIdx.x;
    int tot = 0;
    for (int blk = 0; blk < NSBLK; blk++)
        tot += blockHist[blk * 256 + t];          // coalesced per iteration
    sh[t] = tot;
    __syncthreads();
#pragma unroll
    for (int off = 1; off < 256; off <<= 1) {
        int u = (t >= off) ? sh[t - off] : 0;
        __syncthreads();
        sh[t] += u;
        __syncthreads();
    }
    int run = sh[t] - tot;                        // exclusive bin base
    for (int blk = 0; blk < NSBLK; blk++) {
        base[blk * 256 + t] = run;
        run += blockHist[blk * 256 + t];
    }
}

__global__ __launch_bounds__(256) void scatter_kernel(
    const int* __restrict__ key, const int* __restrict__ base,
    int* __restrict__ perm)
{
    __shared__ int cur[256];
    const int t = threadIdx.x;
    cur[t] = base[blockIdx.x * 256 + t];
    __syncthreads();
    const int gid = blockIdx.x * 256 + t;
    const int k = key[gid];
    const int pos = atomicAdd(&cur[k], 1);        // LDS atomic
    perm[pos] = gid;
}

// ---------------------------------------------------------------------------
// Kernel 2 v3: bilinear sample + maxpool over SORTED pool-groups (unchanged).
//  One group (4 points) per 32-thread slice; 8 groups per 256-thread block,
//  taken consecutively from perm so resident blocks share an image region.
//  Output layout GROUP-MAJOR: pooled[bl][g*128+ch]; w1 split with matching
//  k-permutation so the fc GEMM is unchanged mathematically.
// ---------------------------------------------------------------------------
__global__ __launch_bounds__(256) void sample_pool_kernel(
    const float* __restrict__ lines,
    const float* __restrict__ x,
    const int* __restrict__ perm,
    short* __restrict__ phi,
    short* __restrict__ plo)
{
    const int t  = threadIdx.x;
    const int pg = perm[blockIdx.x * 8 + (t >> 5)];
    const int bl = pg >> 3, g = pg & 7;
    const int b  = bl / LL;
    const int cg = t & 31;                      // channel group (4 ch)
    const float* lp = lines + (size_t)bl * 4;
    const float p0r = lp[0], p0c = lp[1], p1r = lp[2], p1c = lp[3];
    const float* xb = x + (size_t)b * PIX * 128 + cg * 4;

    float mx0 = -INFINITY, mx1 = -INFINITY, mx2 = -INFINITY, mx3 = -INFINITY;
#pragma unroll
    for (int j = 0; j < 4; j++) {
        int tt = g * 4 + j;
        float lam = (float)((double)tt / 31.0);
        float px = p0r * lam + p1r * (1.0f - lam) - 0.5f;
        float py = p0c * lam + p1c * (1.0f - lam) - 0.5f;
        float px0 = fminf(fmaxf(floorf(px), 0.0f), 255.0f);
        float py0 = fminf(fmaxf(floorf(py), 0.0f), 255.0f);
        float px1 = fminf(px0 + 1.0f, 255.0f);
        float py1 = fminf(py0 + 1.0f, 255.0f);
        int ix0 = (int)px0, iy0 = (int)py0, ix1 = (int)px1, iy1 = (int)py1;
        float wx1 = px1 - px, wx0 = px - px0;
        float wy1 = py1 - py, wy0 = py - py0;
        float w00 = wx1 * wy1, w10 = wx0 * wy1;
        float w01 = wx1 * wy0, w11 = wx0 * wy0;
        float4 v00 = *(const float4*)(xb + (size_t)(ix0 * WW + iy0) * 128);
        float4 v10 = *(const float4*)(xb + (size_t)(ix1 * WW + iy0) * 128);
        float4 v01 = *(const float4*)(xb + (size_t)(ix0 * WW + iy1) * 128);
        float4 v11 = *(const float4*)(xb + (size_t)(ix1 * WW + iy1) * 128);
        mx0 = fmaxf(mx0, v00.x * w00 + v10.x * w10 + v01.x * w01 + v11.x * w11);
        mx1 = fmaxf(mx1, v00.y * w00 + v10.y * w10 + v01.y * w01 + v11.y * w11);
        mx2 = fmaxf(mx2, v00.z * w00 + v10.z * w10 + v01.z * w01 + v11.z * w11);
        mx3 = fmaxf(mx3, v00.w * w00 + v10.w * w10 + v01.w * w01 + v11.w * w11);
    }
    float mxs[4] = {mx0, mx1, mx2, mx3};
    short4 h4, l4;
    short hs[4], ls[4];
#pragma unroll
    for (int k = 0; k < 4; k++) {
        hs[k] = f2bf(mxs[k]);
        ls[k] = f2bf(mxs[k] - bf2f(hs[k]));
    }
    h4.x = hs[0]; h4.y = hs[1]; h4.z = hs[2]; h4.w = hs[3];
    l4.x = ls[0]; l4.y = ls[1]; l4.z = ls[2]; l4.w = ls[3];
    const size_t o = (size_t)bl * 1024 + g * 128 + cg * 4;   // group-major
    *(short4*)(phi + o) = h4;
    *(short4*)(plo + o) = l4;
}

// ---------------------------------------------------------------------------
// Kernel 2b: split fp32 weights into bf16 hi/lo (unchanged; fc1 & w2).
// ---------------------------------------------------------------------------
__global__ __launch_bounds__(256) void split_kernel(
    const float* __restrict__ w, short* __restrict__ hi, short* __restrict__ lo)
{
    const int i = (blockIdx.x * 256 + threadIdx.x) * 4;
    float4 v = *(const float4*)(w + i);
    float vv[4] = {v.x, v.y, v.z, v.w};
    short4 h, l;
    short hs[4], ls[4];
#pragma unroll
    for (int j = 0; j < 4; j++) {
        hs[j] = f2bf(vv[j]);
        ls[j] = f2bf(vv[j] - bf2f(hs[j]));
    }
    h.x = hs[0]; h.y = hs[1]; h.z = hs[2]; h.w = hs[3];
    l.x = ls[0]; l.y = ls[1]; l.z = ls[2]; l.w = ls[3];
    *(short4*)(hi + i) = h;
    *(short4*)(lo + i) = l;
}

// ---------------------------------------------------------------------------
// Kernel 2c: split w1 with k-permutation k' = g*128+ch (src k = ch*8+g),
// matching the group-major pooled layout (unchanged).
// ---------------------------------------------------------------------------
__global__ __launch_bounds__(256) void split_permute_kernel(
    const float* __restrict__ w, short* __restrict__ hi, short* __restrict__ lo)
{
    const int i = (blockIdx.x * 256 + threadIdx.x) * 4;   // d*1024 + kp
    const int d = i >> 10, kp = i & 1023;
    const int g = kp >> 7, ch = kp & 127;                 // 4-chunk never crosses g
    float vv[4];
#pragma unroll
    for (int j = 0; j < 4; j++)
        vv[j] = w[(size_t)d * 1024 + (ch + j) * 8 + g];
    short4 h, l;
    short hs[4], ls[4];
#pragma unroll
    for (int j = 0; j < 4; j++) {
        hs[j] = f2bf(vv[j]);
        ls[j] = f2bf(vv[j] - bf2f(hs[j]));
    }
    h.x = hs[0]; h.y = hs[1]; h.z = hs[2]; h.w = hs[3];
    l.x = ls[0]; l.y = ls[1]; l.z = ls[2]; l.w = ls[3];
    *(short4*)(hi + i) = h;
    *(short4*)(lo + i) = l;
}

// ---------------------------------------------------------------------------
// Kernel 3 v4: bf16x3 MFMA GEMM-NT, compiler-pipelined tile body (unchanged).
// ---------------------------------------------------------------------------
#define NT 32                 // K tiles (1024 / 32)
#define BUFS 28672            // shorts per buffer (56 KB)
#define A_LO 6144             // [192][32] hi at 0, lo at 6144
#define B_HI 12288            // [256][32] hi
#define B_LO 20480            // [256][32] lo

template <bool SPLIT_OUT>
__global__ __launch_bounds__(512, 2) void gemm_bf16x3_v4(
    const short* __restrict__ Ahi, const short* __restrict__ Alo,
    const short* __restrict__ Bhi, const short* __restrict__ Blo,
    const float* __restrict__ bias,
    float* __restrict__ Cf, short* __restrict__ Chi, short* __restrict__ Clo,
    int M, int Mtiles)
{
    __shared__ short lds[2 * BUFS];   // 112 KB

    const int t   = threadIdx.x;
    const int bid = blockIdx.x;
    // bijective XCD chunking (m204): nwg = Mtiles*4, xcd = bid&7
    const int nwg = Mtiles * 4;
    const int q = nwg >> 3, r = nwg & 7;
    const int xcd = bid & 7, seq = bid >> 3;
    const int wgid = ((xcd < r) ? xcd * (q + 1) : r * (q + 1) + (xcd - r) * q) + seq;
    const int tileM = wgid >> 2, tileN = wgid & 3;   // M-major: same-A adjacent
    const int m0 = tileM * 192, n0 = tileN * 256;

    const int w = t >> 6, lane = t & 63;
    const int wr = w >> 2;            // 0..1 -> M offset wr*96
    const int wc = w & 3;             // 0..3 -> N offset wc*64
    const int fr = lane & 15;
    // swizzled read chunk: (lane>>4) ^ ((row>>1)&3), row ≡ fr (mod 16)
    const int ksw = (((lane >> 4) ^ ((lane >> 1) & 3)) << 3);
    const int a_row = wr * 96 + fr;
    const int b_row = wc * 64 + fr;

    // --- DMA descriptors: 7 chunks/wave, 56 chunks = 56 KB per K-tile
    const short* gp[7];
    int lp[7];
    {
        const int csrc = (lane & 3) ^ ((lane >> 3) & 3);  // source chunk permute
#pragma unroll
        for (int s = 0; s < 7; s++) {
            int e = w * 7 + s;                            // 0..55
            const short* mp; int mo, j, grow;
            int rl = lane >> 2;                           // row within 16-row chunk
            if (e < 12)      { mp = Ahi; mo = 0;    j = e;      grow = min(m0 + j * 16 + rl, M - 1); }
            else if (e < 24) { mp = Alo; mo = A_LO; j = e - 12; grow = min(m0 + j * 16 + rl, M - 1); }
            else if (e < 40) { mp = Bhi; mo = B_HI; j = e - 24; grow = n0 + j * 16 + rl; }
            else             { mp = Blo; mo = B_LO; j = e - 40; grow = n0 + j * 16 + rl; }
            gp[s] = mp + (size_t)grow * 1024 + csrc * 8;
            lp[s] = mo + j * 512 + lane * 8;              // linear dest, lane*16B
        }
    }

    // --- prologue: tile0 -> buf0, tile1 -> buf1; wait tile0 only (vmcnt(7))
#pragma unroll
    for (int s = 0; s < 7; s++) { load_lds16(gp[s], &lds[lp[s]]); gp[s] += 32; }
#pragma unroll
    for (int s = 0; s < 7; s++) { load_lds16(gp[s], &lds[BUFS + lp[s]]); gp[s] += 32; }
    asm volatile("s_waitcnt vmcnt(7)" ::: "memory");
    wave_barrier();

    float4v acc[6][4];
#pragma unroll
    for (int mf = 0; mf < 6; mf++)
#pragma unroll
        for (int nf = 0; nf < 4; nf++)
            acc[mf][nf] = (float4v){0.f, 0.f, 0.f, 0.f};

    for (int kt = 0; kt < NT; ++kt) {
        const int off = (kt & 1) * BUFS;

        // B fragments for the whole tile (8 reads), then per-M-frag A reads;
        // no lgkmcnt(0) pin: compiler interleaves MFMA with in-flight reads.
        short8_t bh[4], bl[4];
#pragma unroll
        for (int nf = 0; nf < 4; nf++) {
            bh[nf] = *(const short8_t*)&lds[off + B_HI + (b_row + nf * 16) * 32 + ksw];
            bl[nf] = *(const short8_t*)&lds[off + B_LO + (b_row + nf * 16) * 32 + ksw];
        }
#pragma unroll
        for (int mf = 0; mf < 6; mf++) {
            short8_t ah = *(const short8_t*)&lds[off + (a_row + mf * 16) * 32 + ksw];
            short8_t al = *(const short8_t*)&lds[off + A_LO + (a_row + mf * 16) * 32 + ksw];
#pragma unroll
            for (int nf = 0; nf < 4; nf++) {
                MFMA_B16(ah, bh[nf], acc[mf][nf]);
                MFMA_B16(al, bh[nf], acc[mf][nf]);
                MFMA_B16(ah, bl[nf], acc[mf][nf]);
            }
        }

        if (kt < NT - 1) {
            wave_barrier();               // all reads of buf[cur] consumed
            if (kt + 2 < NT) {
                // stage tile kt+2 into buf[cur]; lands during tile kt+1
#pragma unroll
                for (int s = 0; s < 7; s++) {
                    load_lds16(gp[s], &lds[off + lp[s]]); gp[s] += 32;
                }
                asm volatile("s_waitcnt vmcnt(7)" ::: "memory");  // kt+1 landed
            } else {
                asm volatile("s_waitcnt vmcnt(0)" ::: "memory");  // drain last
            }
            wave_barrier();               // publish buf for tile kt+1
        }
    }

    // ---- epilogue
#pragma unroll
    for (int nf = 0; nf < 4; nf++) {
        int ncol = n0 + wc * 64 + nf * 16 + fr;
        float bv = bias[ncol];
#pragma unroll
        for (int mf = 0; mf < 6; mf++) {
            int r0 = m0 + wr * 96 + mf * 16 + ((lane >> 4) << 2);
#pragma unroll
            for (int i2 = 0; i2 < 4; i2++) {
                int rr = r0 + i2;
                if (rr < M) {
                    float v = fmaxf(acc[mf][nf][i2] + bv, 0.0f);
                    if (SPLIT_OUT) {
                        short h = f2bf(v);
                        Chi[(size_t)rr * 1024 + ncol] = h;
                        Clo[(size_t)rr * 1024 + ncol] = f2bf(v - bf2f(h));
                    } else {
                        Cf[(size_t)rr * 1024 + ncol] = v;
                    }
                }
            }
        }
    }
}

// ---------------------------------------------------------------------------
// Kernel 4: fc3 (N=4) + softmax + mask + argmax-class key (unchanged).
// ---------------------------------------------------------------------------
__global__ __launch_bounds__(256) void fc3_softmax_kernel(
    const float* __restrict__ h2, const float* __restrict__ w3,
    const float* __restrict__ b3, float* __restrict__ s, int* __restrict__ keys)
{
    const int m = blockIdx.x * 4 + (threadIdx.x >> 6);
    const int lane = threadIdx.x & 63;
    const float* hp = h2 + (size_t)m * DIM_FC;
    float a0 = 0.f, a1 = 0.f, a2 = 0.f, a3 = 0.f;
    for (int k = lane; k < DIM_FC; k += 64) {
        float hv = hp[k];
        a0 = fmaf(hv, w3[k], a0);
        a1 = fmaf(hv, w3[DIM_FC + k], a1);
        a2 = fmaf(hv, w3[2 * DIM_FC + k], a2);
        a3 = fmaf(hv, w3[3 * DIM_FC + k], a3);
    }
#pragma unroll
    for (int off = 32; off > 0; off >>= 1) {
        a0 += __shfl_down(a0, off, 64);
        a1 += __shfl_down(a1, off, 64);
        a2 += __shfl_down(a2, off, 64);
        a3 += __shfl_down(a3, off, 64);
    }
    if (lane == 0) {
        float l0 = a0 + b3[0], l1 = a1 + b3[1], l2 = a2 + b3[2], l3 = a3 + b3[3];
        float mxl = fmaxf(fmaxf(l0, l1), fmaxf(l2, l3));
        float e0 = expf(l0 - mxl), e1 = expf(l1 - mxl);
        float e2 = expf(l2 - mxl), e3 = expf(l3 - mxl);
        float inv = 1.0f / (e0 + e1 + e2 + e3);
        float s0 = e0 * inv, s1 = e1 * inv, s2 = e2 * inv, s3 = e3 * inv;
        float* sp = s + (size_t)m * 4;
        sp[0] = s0; sp[1] = s1; sp[2] = s2; sp[3] = s3;
        int best = 0; float bv = s0;
        if (s1 > bv) { best = 1; bv = s1; }
        if (s2 > bv) { best = 2; bv = s2; }
        if (s3 > bv) { best = 3; bv = s3; }
        bool msk = ((s1 > 0.25f) || (s2 > 0.25f) || (s3 > 0.25f)) && (s0 < 0.25f);
        keys[m] = msk ? best : -1;
    }
}

// ---------------------------------------------------------------------------
// Kernel 5: stable counting sort by class descending (unchanged).
// ---------------------------------------------------------------------------
__global__ __launch_bounds__(64) void order_kernel(
    const int* __restrict__ keys, int* __restrict__ ord, int* __restrict__ cnts)
{
    const int b = blockIdx.x;
    const int lane = threadIdx.x;
    const int* kb = keys + b * LL;
    int c0 = 0, c1 = 0, c2 = 0, c3 = 0;
    for (int line = lane; line < LL; line += 64) {
        int k = kb[line];
        c0 += (k == 0); c1 += (k == 1); c2 += (k == 2); c3 += (k == 3);
    }
#pragma unroll
    for (int off = 32; off > 0; off >>= 1) {
        c0 += __shfl_down(c0, off, 64);
        c1 += __shfl_down(c1, off, 64);
        c2 += __shfl_down(c2, off, 64);
        c3 += __shfl_down(c3, off, 64);
    }
    int t0 = __shfl(c0, 0, 64), t1 = __shfl(c1, 0, 64);
    int t2 = __shfl(c2, 0, 64), t3 = __shfl(c3, 0, 64);
    if (lane == 0) cnts[b] = t0 + t1 + t2 + t3;
    int base[4];
    base[3] = 0; base[2] = t3; base[1] = t3 + t2; base[0] = t3 + t2 + t1;
    int run[4] = {0, 0, 0, 0};
    const unsigned long long below = (1ull << lane) - 1ull;
    int* ob = ord + b * LL;
    for (int s0 = 0; s0 < LL; s0 += 64) {
        int line = s0 + lane;
        int k = (line < LL) ? kb[line] : -2;
#pragma unroll
        for (int kk = 0; kk < 4; kk++) {
            unsigned long long mask = __ballot(k == kk);
            if (k == kk) {
                int pos = base[kk] + run[kk] + __popcll(mask & below);
                ob[pos] = line;
            }
            run[kk] += __popcll(mask);
        }
    }
}

// ---------------------------------------------------------------------------
// Kernel 6: cyclic fill of 2500 outputs per batch (unchanged).
// ---------------------------------------------------------------------------
__global__ __launch_bounds__(256) void fill_kernel(
    const float* __restrict__ lines, const float* __restrict__ s,
    const int* __restrict__ ord, const int* __restrict__ cnts,
    float* __restrict__ out)
{
    const int i = blockIdx.x * 256 + threadIdx.x;
    if (i >= BB * N_OUT_LINE) return;
    const int b = i / N_OUT_LINE;
    const int j = i % N_OUT_LINE;
    const int cnt = cnts[b];
    float4 lo = {0.f, 0.f, 0.f, 0.f}, sc = {0.f, 0.f, 0.f, 0.f};
    if (cnt > 0) {
        int line = ord[b * LL + (j % cnt)];
        lo = *(const float4*)(lines + ((size_t)b * LL + line) * 4);
        sc = *(const float4*)(s + ((size_t)b * LL + line) * 4);
    }
    *(float4*)(out + (size_t)i * 4) = lo;
    *(float4*)(out + (size_t)(BB * N_OUT_LINE) * 4 + (size_t)i * 4) = sc;
}

// ---------------------------------------------------------------------------
extern "C" void kernel_launch(void* const* d_in, const int* in_sizes, int n_in,
                              void* d_out, int out_size, void* d_ws, size_t ws_size,
                              hipStream_t stream) {
    (void)in_sizes; (void)n_in; (void)out_size; (void)ws_size;
    const float* feature = (const float*)d_in[0];
    const float* lines   = (const float*)d_in[1];
    const float* fc1_w   = (const float*)d_in[2];
    const float* fc1_b   = (const float*)d_in[3];
    const float* w1      = (const float*)d_in[4];
    const float* b1      = (const float*)d_in[5];
    const float* w2      = (const float*)d_in[6];
    const float* b2      = (const float*)d_in[7];
    const float* w3      = (const float*)d_in[8];
    const float* b3      = (const float*)d_in[9];
    float* out = (float*)d_out;

    float* x = (float*)d_ws;
    short* pooled_hi = (short*)(x + (size_t)BB * PIX * 128);
    short* pooled_lo = pooled_hi + (size_t)MM * DIM_FC;
    short* h1hi = (short*)x;
    short* h1lo = h1hi + (size_t)MM * DIM_FC;
    float* h2 = (float*)pooled_hi;
    short* w1hi = (short*)((char*)d_ws + 100u * 1024u * 1024u);
    short* w1lo = w1hi + DIM_FC * DIM_FC;
    short* w2hi = w1lo + DIM_FC * DIM_FC;
    short* w2lo = w2hi + DIM_FC * DIM_FC;
    float* s    = (float*)(pooled_lo + (size_t)MM * DIM_FC);
    int* keys   = (int*)(s + MM * 4);
    int* ord    = keys + MM;
    int* cnts   = ord + MM;
    short* fc1hi = (short*)(cnts + 64);
    short* fc1lo = fc1hi + DIM_LOI * C_IN;
    // sort scratch directly after fc1lo (~217 MiB into 1 GiB ws)
    int* skey  = (int*)(fc1lo + DIM_LOI * C_IN);        // NGRP ints
    int* sperm = skey + NGRP;                           // NGRP ints
    int* sbh   = sperm + NGRP;                          // NSBLK*256 ints
    int* sbase = sbh + NSBLK * 256;                     // NSBLK*256 ints

    split_kernel<<<(DIM_LOI * C_IN) / 1024, 256, 0, stream>>>(fc1_w, fc1hi, fc1lo);
    hist_key_kernel<<<NSBLK, 256, 0, stream>>>(lines, skey, sbh);
    offset_kernel<<<1, 256, 0, stream>>>(sbh, sbase);
    scatter_kernel<<<NSBLK, 256, 0, stream>>>(skey, sbase, sperm);
    conv_mfma_kernel<<<(BB * PIX) / 128, 256, 0, stream>>>(
        feature, fc1hi, fc1lo, fc1_b, x);
    sample_pool_kernel<<<NGRP / 8, 256, 0, stream>>>(
        lines, x, sperm, pooled_hi, pooled_lo);
    split_permute_kernel<<<DIM_FC * DIM_FC / 1024, 256, 0, stream>>>(w1, w1hi, w1lo);
    split_kernel<<<DIM_FC * DIM_FC / 1024, 256, 0, stream>>>(w2, w2hi, w2lo);

    // grid: Mtiles(105) x 4 N-tiles, 512 threads
    const int Mtiles = (MM + 191) / 192;   // 105
    gemm_bf16x3_v4<true><<<Mtiles * 4, 512, 0, stream>>>(
        pooled_hi, pooled_lo, w1hi, w1lo, b1, nullptr, h1hi, h1lo, MM, Mtiles);
    gemm_bf16x3_v4<false><<<Mtiles * 4, 512, 0, stream>>>(
        h1hi, h1lo, w2hi, w2lo, b2, h2, nullptr, nullptr, MM, Mtiles);

    fc3_softmax_kernel<<<MM / 4, 256, 0, stream>>>(h2, w3, b3, s, keys);
    order_kernel<<<BB, 64, 0, stream>>>(keys, ord, cnts);
    fill_kernel<<<(BB * N_OUT_LINE + 255) / 256, 256, 0, stream>>>(
        lines, s, ord, cnts, out);
}

// Round 7
// 842.346 us; speedup vs baseline: 1.2835x; 1.0476x over previous
//
#include <hip/hip_runtime.h>
#include <hip/hip_bf16.h>
#include <math.h>

// Problem constants
#define BB 4
#define C_IN 256
#define HH 256
#define WW 256
#define LL 5000
#define N_PTS0 32
#define N_PTS1 8
#define DIM_LOI 128
#define DIM_FC 1024
#define N_OUT_LINE 2500
#define MM (BB * LL)          // 20000
#define PIX (HH * WW)         // 65536
#define NGRP (MM * N_PTS1)    // 160000 pool groups
#define NSBLK (NGRP / 256)    // 625 sort blocks (exact)

typedef __attribute__((ext_vector_type(8))) short short8_t;   // 8 bf16 in 4 VGPRs
typedef __attribute__((ext_vector_type(4))) float float4v;

// float -> bf16 (RNE) bit tricks
__device__ __forceinline__ short f2bf(float f) {
    union { float f; unsigned u; } c; c.f = f;
    unsigned u = c.u;
    u += 0x7FFFu + ((u >> 16) & 1u);
    return (short)(u >> 16);
}
__device__ __forceinline__ float bf2f(short h) {
    union { unsigned u; float f; } c; c.u = ((unsigned)(unsigned short)h) << 16;
    return c.f;
}

// async global->LDS DMA, 16 B per lane; dest = wave-uniform base + lane*16
__device__ __forceinline__ void load_lds16(const void* g, void* l) {
    __builtin_amdgcn_global_load_lds(
        (const __attribute__((address_space(1))) void*)g,
        (__attribute__((address_space(3))) void*)l, 16, 0, 0);
}

// raw barrier (NO vmcnt drain) with compiler-level memory fences so memory ops
// (ds_read / global_load_lds) cannot be moved across it
__device__ __forceinline__ void wave_barrier() {
    asm volatile("" ::: "memory");
    __builtin_amdgcn_s_barrier();
    asm volatile("" ::: "memory");
}

#define MFMA_B16(a, b, c) \
    c = __builtin_amdgcn_mfma_f32_16x16x32_bf16(a, b, c, 0, 0, 0)

// ---------------------------------------------------------------------------
// Kernel 1: 1x1 conv as bf16x3 MFMA GEMM (unchanged).
// ---------------------------------------------------------------------------
__global__ __launch_bounds__(256) void conv_mfma_kernel(
    const float* __restrict__ feat,   // [B, 256, PIX]
    const short* __restrict__ whi,    // [128, 256] bf16 hi
    const short* __restrict__ wlo,    // [128, 256] bf16 lo
    const float* __restrict__ bias,   // [128]
    float* __restrict__ x)            // [B*PIX, 128]
{
    __shared__ short As_hi[128][40];
    __shared__ short As_lo[128][40];
    __shared__ short Ws_hi[128][40];
    __shared__ short Ws_lo[128][40];

    const int t  = threadIdx.x;
    const int m0 = blockIdx.x * 128;
    const int b  = m0 >> 16;
    const int p0 = m0 & (PIX - 1);
    const float* fb = feat + (size_t)b * C_IN * PIX + p0;

    const int w = t >> 6, lane = t & 63;
    const int wmb = (w >> 1) * 64, wnb = (w & 1) * 64;
    const int fr = lane & 15;
    const int koff = (lane >> 4) << 3;

    const int sp = t & 127;
    const int cg = t >> 7;

    float4v acc[4][4];
#pragma unroll
    for (int mi = 0; mi < 4; mi++)
#pragma unroll
        for (int ni = 0; ni < 4; ni++)
            acc[mi][ni] = (float4v){0.f, 0.f, 0.f, 0.f};

    for (int k0 = 0; k0 < C_IN; k0 += 32) {
#pragma unroll
        for (int i = 0; i < 2; i++) {
            int idx = t + (i << 8);
            int row = idx >> 2;
            int kc  = (idx & 3) << 3;
            *(int4*)&Ws_hi[row][kc] = *(const int4*)(whi + row * C_IN + k0 + kc);
            *(int4*)&Ws_lo[row][kc] = *(const int4*)(wlo + row * C_IN + k0 + kc);
        }
#pragma unroll
        for (int j = 0; j < 8; j++) {
            int c = cg * 16 + j * 2;
            float v0 = fb[(size_t)(k0 + c) * PIX + sp];
            float v1 = fb[(size_t)(k0 + c + 1) * PIX + sp];
            short h0 = f2bf(v0), h1 = f2bf(v1);
            short l0 = f2bf(v0 - bf2f(h0)), l1 = f2bf(v1 - bf2f(h1));
            *(unsigned*)&As_hi[sp][c] =
                (unsigned)(unsigned short)h0 | ((unsigned)(unsigned short)h1 << 16);
            *(unsigned*)&As_lo[sp][c] =
                (unsigned)(unsigned short)l0 | ((unsigned)(unsigned short)l1 << 16);
        }
        __syncthreads();

        short8_t ah[4], al[4];
#pragma unroll
        for (int mi = 0; mi < 4; mi++) {
            ah[mi] = *(const short8_t*)&As_hi[wmb + mi * 16 + fr][koff];
            al[mi] = *(const short8_t*)&As_lo[wmb + mi * 16 + fr][koff];
        }
#pragma unroll
        for (int ni = 0; ni < 4; ni++) {
            short8_t bh = *(const short8_t*)&Ws_hi[wnb + ni * 16 + fr][koff];
            short8_t bl = *(const short8_t*)&Ws_lo[wnb + ni * 16 + fr][koff];
#pragma unroll
            for (int mi = 0; mi < 4; mi++) {
                MFMA_B16(ah[mi], bh, acc[mi][ni]);
                MFMA_B16(al[mi], bh, acc[mi][ni]);
                MFMA_B16(ah[mi], bl, acc[mi][ni]);
            }
        }
        __syncthreads();
    }

#pragma unroll
    for (int ni = 0; ni < 4; ni++) {
        int ncol = wnb + ni * 16 + fr;
        float bv = bias[ncol];
#pragma unroll
        for (int mi = 0; mi < 4; mi++) {
            int r0 = m0 + wmb + mi * 16 + ((lane >> 4) << 2);
#pragma unroll
            for (int i2 = 0; i2 < 4; i2++) {
                x[(size_t)(r0 + i2) * 128 + ncol] = acc[mi][ni][i2] + bv;
            }
        }
    }
}

// ---------------------------------------------------------------------------
// Group sort v2 (unchanged): stable counting sort, LDS atomics only.
// ---------------------------------------------------------------------------
__global__ __launch_bounds__(256) void hist_key_kernel(
    const float* __restrict__ lines, int* __restrict__ key,
    int* __restrict__ blockHist)
{
    __shared__ int h[256];
    const int t = threadIdx.x;
    h[t] = 0;
    __syncthreads();
    const int gid = blockIdx.x * 256 + t;
    const int bl = gid >> 3, g = gid & 7;
    const float* lp = lines + (size_t)bl * 4;
    const float lam = (float)((double)(g * 4) / 31.0);
    float px = lp[0] * lam + lp[2] * (1.0f - lam) - 0.5f;
    float py = lp[1] * lam + lp[3] * (1.0f - lam) - 0.5f;
    int ix = min(max((int)floorf(px), 0), 255);
    int iy = min(max((int)floorf(py), 0), 255);
    const int b = bl / LL;
    const int k = b * 64 + (ix >> 5) * 8 + (iy >> 5);
    key[gid] = k;
    atomicAdd(&h[k], 1);          // LDS atomic
    __syncthreads();
    blockHist[blockIdx.x * 256 + t] = h[t];
}

__global__ __launch_bounds__(256) void offset_kernel(
    const int* __restrict__ blockHist, int* __restrict__ base)
{
    __shared__ int sh[256];
    const int t = threadIdx.x;
    int tot = 0;
    for (int blk = 0; blk < NSBLK; blk++)
        tot += blockHist[blk * 256 + t];          // coalesced per iteration
    sh[t] = tot;
    __syncthreads();
#pragma unroll
    for (int off = 1; off < 256; off <<= 1) {
        int u = (t >= off) ? sh[t - off] : 0;
        __syncthreads();
        sh[t] += u;
        __syncthreads();
    }
    int run = sh[t] - tot;                        // exclusive bin base
    for (int blk = 0; blk < NSBLK; blk++) {
        base[blk * 256 + t] = run;
        run += blockHist[blk * 256 + t];
    }
}

__global__ __launch_bounds__(256) void scatter_kernel(
    const int* __restrict__ key, const int* __restrict__ base,
    int* __restrict__ perm)
{
    __shared__ int cur[256];
    const int t = threadIdx.x;
    cur[t] = base[blockIdx.x * 256 + t];
    __syncthreads();
    const int gid = blockIdx.x * 256 + t;
    const int k = key[gid];
    const int pos = atomicAdd(&cur[k], 1);        // LDS atomic
    perm[pos] = gid;
}

// ---------------------------------------------------------------------------
// Kernel 2 v3: bilinear sample + maxpool over SORTED pool-groups (unchanged).
// ---------------------------------------------------------------------------
__global__ __launch_bounds__(256) void sample_pool_kernel(
    const float* __restrict__ lines,
    const float* __restrict__ x,
    const int* __restrict__ perm,
    short* __restrict__ phi,
    short* __restrict__ plo)
{
    const int t  = threadIdx.x;
    const int pg = perm[blockIdx.x * 8 + (t >> 5)];
    const int bl = pg >> 3, g = pg & 7;
    const int b  = bl / LL;
    const int cg = t & 31;                      // channel group (4 ch)
    const float* lp = lines + (size_t)bl * 4;
    const float p0r = lp[0], p0c = lp[1], p1r = lp[2], p1c = lp[3];
    const float* xb = x + (size_t)b * PIX * 128 + cg * 4;

    float mx0 = -INFINITY, mx1 = -INFINITY, mx2 = -INFINITY, mx3 = -INFINITY;
#pragma unroll
    for (int j = 0; j < 4; j++) {
        int tt = g * 4 + j;
        float lam = (float)((double)tt / 31.0);
        float px = p0r * lam + p1r * (1.0f - lam) - 0.5f;
        float py = p0c * lam + p1c * (1.0f - lam) - 0.5f;
        float px0 = fminf(fmaxf(floorf(px), 0.0f), 255.0f);
        float py0 = fminf(fmaxf(floorf(py), 0.0f), 255.0f);
        float px1 = fminf(px0 + 1.0f, 255.0f);
        float py1 = fminf(py0 + 1.0f, 255.0f);
        int ix0 = (int)px0, iy0 = (int)py0, ix1 = (int)px1, iy1 = (int)py1;
        float wx1 = px1 - px, wx0 = px - px0;
        float wy1 = py1 - py, wy0 = py - py0;
        float w00 = wx1 * wy1, w10 = wx0 * wy1;
        float w01 = wx1 * wy0, w11 = wx0 * wy0;
        float4 v00 = *(const float4*)(xb + (size_t)(ix0 * WW + iy0) * 128);
        float4 v10 = *(const float4*)(xb + (size_t)(ix1 * WW + iy0) * 128);
        float4 v01 = *(const float4*)(xb + (size_t)(ix0 * WW + iy1) * 128);
        float4 v11 = *(const float4*)(xb + (size_t)(ix1 * WW + iy1) * 128);
        mx0 = fmaxf(mx0, v00.x * w00 + v10.x * w10 + v01.x * w01 + v11.x * w11);
        mx1 = fmaxf(mx1, v00.y * w00 + v10.y * w10 + v01.y * w01 + v11.y * w11);
        mx2 = fmaxf(mx2, v00.z * w00 + v10.z * w10 + v01.z * w01 + v11.z * w11);
        mx3 = fmaxf(mx3, v00.w * w00 + v10.w * w10 + v01.w * w01 + v11.w * w11);
    }
    float mxs[4] = {mx0, mx1, mx2, mx3};
    short4 h4, l4;
    short hs[4], ls[4];
#pragma unroll
    for (int k = 0; k < 4; k++) {
        hs[k] = f2bf(mxs[k]);
        ls[k] = f2bf(mxs[k] - bf2f(hs[k]));
    }
    h4.x = hs[0]; h4.y = hs[1]; h4.z = hs[2]; h4.w = hs[3];
    l4.x = ls[0]; l4.y = ls[1]; l4.z = ls[2]; l4.w = ls[3];
    const size_t o = (size_t)bl * 1024 + g * 128 + cg * 4;   // group-major
    *(short4*)(phi + o) = h4;
    *(short4*)(plo + o) = l4;
}

// ---------------------------------------------------------------------------
// Kernel 2b: split fp32 weights into bf16 hi/lo (unchanged; fc1 & w2).
// ---------------------------------------------------------------------------
__global__ __launch_bounds__(256) void split_kernel(
    const float* __restrict__ w, short* __restrict__ hi, short* __restrict__ lo)
{
    const int i = (blockIdx.x * 256 + threadIdx.x) * 4;
    float4 v = *(const float4*)(w + i);
    float vv[4] = {v.x, v.y, v.z, v.w};
    short4 h, l;
    short hs[4], ls[4];
#pragma unroll
    for (int j = 0; j < 4; j++) {
        hs[j] = f2bf(vv[j]);
        ls[j] = f2bf(vv[j] - bf2f(hs[j]));
    }
    h.x = hs[0]; h.y = hs[1]; h.z = hs[2]; h.w = hs[3];
    l.x = ls[0]; l.y = ls[1]; l.z = ls[2]; l.w = ls[3];
    *(short4*)(hi + i) = h;
    *(short4*)(lo + i) = l;
}

// ---------------------------------------------------------------------------
// Kernel 2c: split w1 with k-permutation k' = g*128+ch (unchanged).
// ---------------------------------------------------------------------------
__global__ __launch_bounds__(256) void split_permute_kernel(
    const float* __restrict__ w, short* __restrict__ hi, short* __restrict__ lo)
{
    const int i = (blockIdx.x * 256 + threadIdx.x) * 4;   // d*1024 + kp
    const int d = i >> 10, kp = i & 1023;
    const int g = kp >> 7, ch = kp & 127;                 // 4-chunk never crosses g
    float vv[4];
#pragma unroll
    for (int j = 0; j < 4; j++)
        vv[j] = w[(size_t)d * 1024 + (ch + j) * 8 + g];
    short4 h, l;
    short hs[4], ls[4];
#pragma unroll
    for (int j = 0; j < 4; j++) {
        hs[j] = f2bf(vv[j]);
        ls[j] = f2bf(vv[j] - bf2f(hs[j]));
    }
    h.x = hs[0]; h.y = hs[1]; h.z = hs[2]; h.w = hs[3];
    l.x = ls[0]; l.y = ls[1]; l.z = ls[2]; l.w = ls[3];
    *(short4*)(hi + i) = h;
    *(short4*)(lo + i) = l;
}

// ---------------------------------------------------------------------------
// Kernel 3 v5: bf16x3 MFMA GEMM-NT, LDS-traffic-optimized geometry.
//  Round-6 PMC model: LDS read stream (224 KB/tile @85 B/cyc = 1920 cyc)
//  dominates MFMA (691 cyc) -> MfmaUtil 34%. Fix: per-wave tile 96x64 ->
//  160x64 (BM 192->320): 229 KB/tile for 15.7 MFLOP = 68.6 FLOP/LDS-byte
//  (vs 57.6), and grid 420 -> 252 blocks (~1/CU, kills the 2-round makespan).
//  Same vmcnt-counted 2-buffer pipeline (9 chunks/wave/tile -> vmcnt(9)),
//  same swizzle, same pass order -> bit-identical numerics.
//  LDS: 2 x 72 KB = 144 KB. acc[10][4] ~ 160 VGPR, target <256 (512,2).
// ---------------------------------------------------------------------------
#define NT 32                 // K tiles (1024 / 32)
#define BUFS 36864            // shorts per buffer (72 KB)
#define A_LO 10240            // [320][32] hi at 0, lo at 10240 (shorts)
#define B_HI 20480            // [256][32] hi
#define B_LO 28672            // [256][32] lo

template <bool SPLIT_OUT>
__global__ __launch_bounds__(512, 2) void gemm_bf16x3_v5(
    const short* __restrict__ Ahi, const short* __restrict__ Alo,
    const short* __restrict__ Bhi, const short* __restrict__ Blo,
    const float* __restrict__ bias,
    float* __restrict__ Cf, short* __restrict__ Chi, short* __restrict__ Clo,
    int M, int Mtiles)
{
    __shared__ short lds[2 * BUFS];   // 144 KB

    const int t   = threadIdx.x;
    const int bid = blockIdx.x;
    // bijective XCD chunking (m204): nwg = Mtiles*4, xcd = bid&7
    const int nwg = Mtiles * 4;
    const int q = nwg >> 3, r = nwg & 7;
    const int xcd = bid & 7, seq = bid >> 3;
    const int wgid = ((xcd < r) ? xcd * (q + 1) : r * (q + 1) + (xcd - r) * q) + seq;
    const int tileM = wgid >> 2, tileN = wgid & 3;   // M-major: same-A adjacent
    const int m0 = tileM * 320, n0 = tileN * 256;

    const int w = t >> 6, lane = t & 63;
    const int wr = w >> 2;            // 0..1 -> M offset wr*160
    const int wc = w & 3;             // 0..3 -> N offset wc*64
    const int fr = lane & 15;
    // swizzled read chunk: (lane>>4) ^ ((row>>1)&3), row ≡ fr (mod 16)
    const int ksw = (((lane >> 4) ^ ((lane >> 1) & 3)) << 3);
    const int a_row = wr * 160 + fr;
    const int b_row = wc * 64 + fr;

    // --- DMA descriptors: 9 chunks/wave, 72 chunks = 72 KB per K-tile
    const short* gp[9];
    int lp[9];
    {
        const int csrc = (lane & 3) ^ ((lane >> 3) & 3);  // source chunk permute
#pragma unroll
        for (int s = 0; s < 9; s++) {
            int e = w * 9 + s;                            // 0..71
            const short* mp; int mo, j, grow;
            int rl = lane >> 2;                           // row within 16-row chunk
            if (e < 20)      { mp = Ahi; mo = 0;    j = e;      grow = min(m0 + j * 16 + rl, M - 1); }
            else if (e < 40) { mp = Alo; mo = A_LO; j = e - 20; grow = min(m0 + j * 16 + rl, M - 1); }
            else if (e < 56) { mp = Bhi; mo = B_HI; j = e - 40; grow = n0 + j * 16 + rl; }
            else             { mp = Blo; mo = B_LO; j = e - 56; grow = n0 + j * 16 + rl; }
            gp[s] = mp + (size_t)grow * 1024 + csrc * 8;
            lp[s] = mo + j * 512 + lane * 8;              // linear dest, lane*16B
        }
    }

    // --- prologue: tile0 -> buf0, tile1 -> buf1; wait tile0 only (vmcnt(9))
#pragma unroll
    for (int s = 0; s < 9; s++) { load_lds16(gp[s], &lds[lp[s]]); gp[s] += 32; }
#pragma unroll
    for (int s = 0; s < 9; s++) { load_lds16(gp[s], &lds[BUFS + lp[s]]); gp[s] += 32; }
    asm volatile("s_waitcnt vmcnt(9)" ::: "memory");
    wave_barrier();

    float4v acc[10][4];
#pragma unroll
    for (int mf = 0; mf < 10; mf++)
#pragma unroll
        for (int nf = 0; nf < 4; nf++)
            acc[mf][nf] = (float4v){0.f, 0.f, 0.f, 0.f};

    for (int kt = 0; kt < NT; ++kt) {
        const int off = (kt & 1) * BUFS;

        // B fragments for the whole tile (8 reads), then per-M-frag A reads;
        // no lgkmcnt(0) pin: compiler interleaves MFMA with in-flight reads.
        short8_t bh[4], bl[4];
#pragma unroll
        for (int nf = 0; nf < 4; nf++) {
            bh[nf] = *(const short8_t*)&lds[off + B_HI + (b_row + nf * 16) * 32 + ksw];
            bl[nf] = *(const short8_t*)&lds[off + B_LO + (b_row + nf * 16) * 32 + ksw];
        }
#pragma unroll
        for (int mf = 0; mf < 10; mf++) {
            short8_t ah = *(const short8_t*)&lds[off + (a_row + mf * 16) * 32 + ksw];
            short8_t al = *(const short8_t*)&lds[off + A_LO + (a_row + mf * 16) * 32 + ksw];
#pragma unroll
            for (int nf = 0; nf < 4; nf++) {
                MFMA_B16(ah, bh[nf], acc[mf][nf]);
                MFMA_B16(al, bh[nf], acc[mf][nf]);
                MFMA_B16(ah, bl[nf], acc[mf][nf]);
            }
        }

        if (kt < NT - 1) {
            wave_barrier();               // all reads of buf[cur] consumed
            if (kt + 2 < NT) {
                // stage tile kt+2 into buf[cur]; lands during tile kt+1
#pragma unroll
                for (int s = 0; s < 9; s++) {
                    load_lds16(gp[s], &lds[off + lp[s]]); gp[s] += 32;
                }
                asm volatile("s_waitcnt vmcnt(9)" ::: "memory");  // kt+1 landed
            } else {
                asm volatile("s_waitcnt vmcnt(0)" ::: "memory");  // drain last
            }
            wave_barrier();               // publish buf for tile kt+1
        }
    }

    // ---- epilogue
#pragma unroll
    for (int nf = 0; nf < 4; nf++) {
        int ncol = n0 + wc * 64 + nf * 16 + fr;
        float bv = bias[ncol];
#pragma unroll
        for (int mf = 0; mf < 10; mf++) {
            int r0 = m0 + wr * 160 + mf * 16 + ((lane >> 4) << 2);
#pragma unroll
            for (int i2 = 0; i2 < 4; i2++) {
                int rr = r0 + i2;
                if (rr < M) {
                    float v = fmaxf(acc[mf][nf][i2] + bv, 0.0f);
                    if (SPLIT_OUT) {
                        short h = f2bf(v);
                        Chi[(size_t)rr * 1024 + ncol] = h;
                        Clo[(size_t)rr * 1024 + ncol] = f2bf(v - bf2f(h));
                    } else {
                        Cf[(size_t)rr * 1024 + ncol] = v;
                    }
                }
            }
        }
    }
}

// ---------------------------------------------------------------------------
// Kernel 4: fc3 (N=4) + softmax + mask + argmax-class key (unchanged).
// ---------------------------------------------------------------------------
__global__ __launch_bounds__(256) void fc3_softmax_kernel(
    const float* __restrict__ h2, const float* __restrict__ w3,
    const float* __restrict__ b3, float* __restrict__ s, int* __restrict__ keys)
{
    const int m = blockIdx.x * 4 + (threadIdx.x >> 6);
    const int lane = threadIdx.x & 63;
    const float* hp = h2 + (size_t)m * DIM_FC;
    float a0 = 0.f, a1 = 0.f, a2 = 0.f, a3 = 0.f;
    for (int k = lane; k < DIM_FC; k += 64) {
        float hv = hp[k];
        a0 = fmaf(hv, w3[k], a0);
        a1 = fmaf(hv, w3[DIM_FC + k], a1);
        a2 = fmaf(hv, w3[2 * DIM_FC + k], a2);
        a3 = fmaf(hv, w3[3 * DIM_FC + k], a3);
    }
#pragma unroll
    for (int off = 32; off > 0; off >>= 1) {
        a0 += __shfl_down(a0, off, 64);
        a1 += __shfl_down(a1, off, 64);
        a2 += __shfl_down(a2, off, 64);
        a3 += __shfl_down(a3, off, 64);
    }
    if (lane == 0) {
        float l0 = a0 + b3[0], l1 = a1 + b3[1], l2 = a2 + b3[2], l3 = a3 + b3[3];
        float mxl = fmaxf(fmaxf(l0, l1), fmaxf(l2, l3));
        float e0 = expf(l0 - mxl), e1 = expf(l1 - mxl);
        float e2 = expf(l2 - mxl), e3 = expf(l3 - mxl);
        float inv = 1.0f / (e0 + e1 + e2 + e3);
        float s0 = e0 * inv, s1 = e1 * inv, s2 = e2 * inv, s3 = e3 * inv;
        float* sp = s + (size_t)m * 4;
        sp[0] = s0; sp[1] = s1; sp[2] = s2; sp[3] = s3;
        int best = 0; float bv = s0;
        if (s1 > bv) { best = 1; bv = s1; }
        if (s2 > bv) { best = 2; bv = s2; }
        if (s3 > bv) { best = 3; bv = s3; }
        bool msk = ((s1 > 0.25f) || (s2 > 0.25f) || (s3 > 0.25f)) && (s0 < 0.25f);
        keys[m] = msk ? best : -1;
    }
}

// ---------------------------------------------------------------------------
// Kernel 5: stable counting sort by class descending (unchanged).
// ---------------------------------------------------------------------------
__global__ __launch_bounds__(64) void order_kernel(
    const int* __restrict__ keys, int* __restrict__ ord, int* __restrict__ cnts)
{
    const int b = blockIdx.x;
    const int lane = threadIdx.x;
    const int* kb = keys + b * LL;
    int c0 = 0, c1 = 0, c2 = 0, c3 = 0;
    for (int line = lane; line < LL; line += 64) {
        int k = kb[line];
        c0 += (k == 0); c1 += (k == 1); c2 += (k == 2); c3 += (k == 3);
    }
#pragma unroll
    for (int off = 32; off > 0; off >>= 1) {
        c0 += __shfl_down(c0, off, 64);
        c1 += __shfl_down(c1, off, 64);
        c2 += __shfl_down(c2, off, 64);
        c3 += __shfl_down(c3, off, 64);
    }
    int t0 = __shfl(c0, 0, 64), t1 = __shfl(c1, 0, 64);
    int t2 = __shfl(c2, 0, 64), t3 = __shfl(c3, 0, 64);
    if (lane == 0) cnts[b] = t0 + t1 + t2 + t3;
    int base[4];
    base[3] = 0; base[2] = t3; base[1] = t3 + t2; base[0] = t3 + t2 + t1;
    int run[4] = {0, 0, 0, 0};
    const unsigned long long below = (1ull << lane) - 1ull;
    int* ob = ord + b * LL;
    for (int s0 = 0; s0 < LL; s0 += 64) {
        int line = s0 + lane;
        int k = (line < LL) ? kb[line] : -2;
#pragma unroll
        for (int kk = 0; kk < 4; kk++) {
            unsigned long long mask = __ballot(k == kk);
            if (k == kk) {
                int pos = base[kk] + run[kk] + __popcll(mask & below);
                ob[pos] = line;
            }
            run[kk] += __popcll(mask);
        }
    }
}

// ---------------------------------------------------------------------------
// Kernel 6: cyclic fill of 2500 outputs per batch (unchanged).
// ---------------------------------------------------------------------------
__global__ __launch_bounds__(256) void fill_kernel(
    const float* __restrict__ lines, const float* __restrict__ s,
    const int* __restrict__ ord, const int* __restrict__ cnts,
    float* __restrict__ out)
{
    const int i = blockIdx.x * 256 + threadIdx.x;
    if (i >= BB * N_OUT_LINE) return;
    const int b = i / N_OUT_LINE;
    const int j = i % N_OUT_LINE;
    const int cnt = cnts[b];
    float4 lo = {0.f, 0.f, 0.f, 0.f}, sc = {0.f, 0.f, 0.f, 0.f};
    if (cnt > 0) {
        int line = ord[b * LL + (j % cnt)];
        lo = *(const float4*)(lines + ((size_t)b * LL + line) * 4);
        sc = *(const float4*)(s + ((size_t)b * LL + line) * 4);
    }
    *(float4*)(out + (size_t)i * 4) = lo;
    *(float4*)(out + (size_t)(BB * N_OUT_LINE) * 4 + (size_t)i * 4) = sc;
}

// ---------------------------------------------------------------------------
extern "C" void kernel_launch(void* const* d_in, const int* in_sizes, int n_in,
                              void* d_out, int out_size, void* d_ws, size_t ws_size,
                              hipStream_t stream) {
    (void)in_sizes; (void)n_in; (void)out_size; (void)ws_size;
    const float* feature = (const float*)d_in[0];
    const float* lines   = (const float*)d_in[1];
    const float* fc1_w   = (const float*)d_in[2];
    const float* fc1_b   = (const float*)d_in[3];
    const float* w1      = (const float*)d_in[4];
    const float* b1      = (const float*)d_in[5];
    const float* w2      = (const float*)d_in[6];
    const float* b2      = (const float*)d_in[7];
    const float* w3      = (const float*)d_in[8];
    const float* b3      = (const float*)d_in[9];
    float* out = (float*)d_out;

    float* x = (float*)d_ws;
    short* pooled_hi = (short*)(x + (size_t)BB * PIX * 128);
    short* pooled_lo = pooled_hi + (size_t)MM * DIM_FC;
    short* h1hi = (short*)x;
    short* h1lo = h1hi + (size_t)MM * DIM_FC;
    float* h2 = (float*)pooled_hi;
    short* w1hi = (short*)((char*)d_ws + 100u * 1024u * 1024u);
    short* w1lo = w1hi + DIM_FC * DIM_FC;
    short* w2hi = w1lo + DIM_FC * DIM_FC;
    short* w2lo = w2hi + DIM_FC * DIM_FC;
    float* s    = (float*)(pooled_lo + (size_t)MM * DIM_FC);
    int* keys   = (int*)(s + MM * 4);
    int* ord    = keys + MM;
    int* cnts   = ord + MM;
    short* fc1hi = (short*)(cnts + 64);
    short* fc1lo = fc1hi + DIM_LOI * C_IN;
    // sort scratch directly after fc1lo (~217 MiB into 1 GiB ws)
    int* skey  = (int*)(fc1lo + DIM_LOI * C_IN);        // NGRP ints
    int* sperm = skey + NGRP;                           // NGRP ints
    int* sbh   = sperm + NGRP;                          // NSBLK*256 ints
    int* sbase = sbh + NSBLK * 256;                     // NSBLK*256 ints

    split_kernel<<<(DIM_LOI * C_IN) / 1024, 256, 0, stream>>>(fc1_w, fc1hi, fc1lo);
    hist_key_kernel<<<NSBLK, 256, 0, stream>>>(lines, skey, sbh);
    offset_kernel<<<1, 256, 0, stream>>>(sbh, sbase);
    scatter_kernel<<<NSBLK, 256, 0, stream>>>(skey, sbase, sperm);
    conv_mfma_kernel<<<(BB * PIX) / 128, 256, 0, stream>>>(
        feature, fc1hi, fc1lo, fc1_b, x);
    sample_pool_kernel<<<NGRP / 8, 256, 0, stream>>>(
        lines, x, sperm, pooled_hi, pooled_lo);
    split_permute_kernel<<<DIM_FC * DIM_FC / 1024, 256, 0, stream>>>(w1, w1hi, w1lo);
    split_kernel<<<DIM_FC * DIM_FC / 1024, 256, 0, stream>>>(w2, w2hi, w2lo);

    // grid: Mtiles(63) x 4 N-tiles = 252 blocks (~1/CU), 512 threads
    const int Mtiles = (MM + 319) / 320;   // 63
    gemm_bf16x3_v5<true><<<Mtiles * 4, 512, 0, stream>>>(
        pooled_hi, pooled_lo, w1hi, w1lo, b1, nullptr, h1hi, h1lo, MM, Mtiles);
    gemm_bf16x3_v5<false><<<Mtiles * 4, 512, 0, stream>>>(
        h1hi, h1lo, w2hi, w2lo, b2, h2, nullptr, nullptr, MM, Mtiles);

    fc3_softmax_kernel<<<MM / 4, 256, 0, stream>>>(h2, w3, b3, s, keys);
    order_kernel<<<BB, 64, 0, stream>>>(keys, ord, cnts);
    fill_kernel<<<(BB * N_OUT_LINE + 255) / 256, 256, 0, stream>>>(
        lines, s, ord, cnts, out);
}